// Round 7
// baseline (7563.532 us; speedup 1.0000x reference)
//
#include <hip/hip_runtime.h>

typedef __bf16 bf16;
typedef __bf16 bf16x8 __attribute__((ext_vector_type(8)));
typedef float f32x4 __attribute__((ext_vector_type(4)));
typedef unsigned int u32;
typedef unsigned long long u64;

#define T_STEPS 1024
#define BATCH 128
#define DIM 256      // D
#define HID 512      // H
#define NB 128       // 8 batch-groups x 16 col-groups
#define GB 16        // batches per group

__device__ __forceinline__ f32x4 mfma_bf16(bf16x8 a, bf16x8 b, f32x4 c) {
  return __builtin_amdgcn_mfma_f32_16x16x32_bf16(a, b, c, 0, 0, 0);
}
__device__ __forceinline__ float fast_sigmoid(float v) {
  return __builtin_amdgcn_rcpf(1.f + __expf(-v));
}
__device__ __forceinline__ float fast_tanh(float v) {
  return 2.f * __builtin_amdgcn_rcpf(1.f + __expf(-2.f * v)) - 1.f;
}
__device__ __forceinline__ bf16x8 cvt8(const float* p) {
  float4 a = *(const float4*)p;
  float4 b = *(const float4*)(p + 4);
  bf16x8 r;
  r[0] = (bf16)a.x; r[1] = (bf16)a.y; r[2] = (bf16)a.z; r[3] = (bf16)a.w;
  r[4] = (bf16)b.x; r[5] = (bf16)b.y; r[6] = (bf16)b.z; r[7] = (bf16)b.w;
  return r;
}
__device__ __forceinline__ u64 ld_agent(const u64* p) {
  return __hip_atomic_load(p, __ATOMIC_RELAXED, __HIP_MEMORY_SCOPE_AGENT);
}
__device__ __forceinline__ void st_agent(u64* p, u64 v) {
  __hip_atomic_store(p, v, __ATOMIC_RELAXED, __HIP_MEMORY_SCOPE_AGENT);
}
// pack one h value with its sequence number: low16 = bf16(h), high16 = seq
__device__ __forceinline__ u32 pack_hs(float h, u32 seq) {
  return (u32)__builtin_bit_cast(unsigned short, (bf16)h) | (seq << 16);
}
__device__ __forceinline__ bf16 bits16(u64 v) {
  return __builtin_bit_cast(bf16, (unsigned short)(v & 0xffffu));
}
// 4 seq-u64 (8 seq-u32) -> 8 bf16 values (strip seqs)
__device__ __forceinline__ bf16x8 seq8(u64 a, u64 b, u64 c, u64 d) {
  bf16x8 r;
  r[0] = bits16(a); r[1] = bits16(a >> 32);
  r[2] = bits16(b); r[3] = bits16(b >> 32);
  r[4] = bits16(c); r[5] = bits16(c >> 32);
  r[6] = bits16(d); r[7] = bits16(d >> 32);
  return r;
}

// ws layout: hw[2][BATCH][HID] u32 ring (512 KB). Each u32 = bf16(h) | seq<<16.
// h_t lives in slot (t & 1) with seq == t. memset-0 == valid h_0 (seq 0, h 0).
//
// SEQ-EMBEDDED SYNC (no flags, no publish barrier):
//  - producers store h_{t+1} as (bf16|seq t+1) via aligned 8B agent stores
//    (single-copy atomic: each u64 self-validates; no store->flag ordering).
//  - consumers poll their gather lines until every u64's embedded seq == t;
//    detection and data arrive in the SAME MALL round trip.
//  - WAR safety: a block passes its step-t poll only after every wave of
//    every peer (incl. its own block) stored seq-t h, which certifies those
//    waves' step-(t-1) gather loads and LDS reads completed -> overwriting
//    ring slot (t+1)&1 (= h_{t-1}) and the LDS tile is safe. One barrier/step
//    (LDS write -> MFMA read); no end-of-step barrier.
//
// Partition (HW-validated r4): bg = bid & 7, cg = bid >> 3. Block owns batches
// [bg*16, bg*16+16) x h-cols [cg*32, cg*32+32). Weights in registers (192 VGPR
// of frags); full 512-VGPR budget at 1 wave/SIMD.
__global__ __launch_bounds__(256, 1) void lstm_persist(
    const float* __restrict__ x, const float* __restrict__ Wx,
    const float* __restrict__ bx, const float* __restrict__ Wh,
    const float* __restrict__ bh, const float* __restrict__ Wfc,
    const float* __restrict__ bfc, float* __restrict__ out,
    u32* hw) {
  const int tid = threadIdx.x;
  const int bid = blockIdx.x;
  const int wave = tid >> 6;
  const int lane = tid & 63;
  const int n = lane & 15;      // MFMA column / A-row selector
  const int quad = lane >> 4;   // k-chunk selector
  const int sub = n & 3;        // col-sub within 4-group
  const int bg = bid & 7;       // batch group 0..7
  const int cg = bid >> 3;      // col group 0..15
  const int mbase = bg * GB;    // first batch row of this block

  __shared__ bf16 lds_h[16][520];  // staged h tile for this group (16.6 KB)

  // ---- this lane's two gate rows (N-tiles nt=0,1): R = gate*HID + hcol ----
  const int R0 = (n >> 2) * HID + cg * 32 + wave * 8 + sub;
  const int R1 = R0 + 4;
  const float bias0 = bx[R0] + bh[R0];
  const float bias1 = bx[R1] + bh[R1];
  const f32x4 bv0 = {bias0, bias0, bias0, bias0};
  const f32x4 bv1 = {bias1, bias1, bias1, bias1};

  // ---- weight fragments in registers (fixed for all 1024 steps) ----
  bf16x8 whf0[16], whf1[16];
#pragma unroll
  for (int k = 0; k < 16; ++k) {
    whf0[k] = cvt8(Wh + (size_t)R0 * HID + quad * 8 + k * 32);
    whf1[k] = cvt8(Wh + (size_t)R1 * HID + quad * 8 + k * 32);
  }
  bf16x8 wxf0[8], wxf1[8];
#pragma unroll
  for (int k = 0; k < 8; ++k) {
    wxf0[k] = cvt8(Wx + (size_t)R0 * DIM + quad * 8 + k * 32);
    wxf1[k] = cvt8(Wx + (size_t)R1 * DIM + quad * 8 + k * 32);
  }

  float cst[2][4];
#pragma unroll
  for (int a = 0; a < 2; ++a)
#pragma unroll
    for (int r = 0; r < 4; ++r) cst[a][r] = 0.f;

  const int qb = lane & 48;
  const int srcf = qb | (4 + sub);
  const int srcg = qb | (8 + sub);
  const int srco = qb | (12 + sub);

  // gather map: thread -> (row grow, 32 u32-cols at gchunk*32); 128B/thread.
  // grow = tid&15 keeps LDS writes <=2-way bank-aliased (free).
  const int grow = tid & 15;
  const int gchunk = tid >> 4;

  for (int t = 0; t < T_STEPS; ++t) {
    u32* slot_rd = hw + (size_t)(t & 1) * (BATCH * HID);
    u32* slot_wr = hw + (size_t)((t + 1) & 1) * (BATCH * HID);

    f32x4 acc0 = bv0, acc1 = bv1;

    // ---- x_t @ Wx^T: independent of other blocks, overlaps peers' stores ----
    const float* x0p = x + (size_t)((mbase + n) * 1024 + t) * DIM + quad * 8;
#pragma unroll
    for (int k = 0; k < 8; ++k) {
      bf16x8 A = cvt8(x0p + k * 32);
      acc0 = mfma_bf16(A, wxf0[k], acc0);
      acc1 = mfma_bf16(A, wxf1[k], acc1);
    }

    // ---- fused poll+gather: load this thread's 16 u64, accept when every
    // embedded seq == t (detection IS the data round trip) ----
    {
      const u64* src = (const u64*)(slot_rd + (size_t)(mbase + grow) * HID + gchunk * 32);
      bool done = false;
      while (true) {
        if (!done) {
          u64 hv[16];
#pragma unroll
          for (int j = 0; j < 16; ++j) hv[j] = ld_agent(src + j);
          bool v = true;
#pragma unroll
          for (int j = 0; j < 16; ++j) v &= (((hv[j] >> 16) & 0xffffu) == (u32)t);
          if (v) {
            u32* dst = (u32*)(&lds_h[grow][gchunk * 32]);
#pragma unroll
            for (int j = 0; j < 16; ++j) {
              dst[j] = (u32)(hv[j] & 0xffffu) | ((u32)((hv[j] >> 32) & 0xffffu) << 16);
            }
            done = true;
          }
        }
        if (__all(done)) break;
        __builtin_amdgcn_s_sleep(1);
      }
    }
    __syncthreads();  // LDS tile complete (WAR vs prev step: poll-certified)

    // ---- h @ Wh^T: A from LDS (shared across nt), B from registers ----
#pragma unroll
    for (int k = 0; k < 16; ++k) {
      bf16x8 A = *(const bf16x8*)(&lds_h[n][quad * 8 + k * 32]);
      acc0 = mfma_bf16(A, whf0[k], acc0);
      acc1 = mfma_bf16(A, whf1[k], acc1);
    }

    // ---- gate nonlinearities + cell update ----
    f32x4 accs[2] = {acc0, acc1};
#pragma unroll
    for (int nt = 0; nt < 2; ++nt) {
#pragma unroll
      for (int r = 0; r < 4; ++r) {
        float v = accs[nt][r];
        float s = fast_sigmoid(v);
        float th = fast_tanh(v);
        float pv = (n >= 8 && n < 12) ? th : s;  // g-gate lanes: tanh
        float fv = __shfl(pv, srcf, 64);
        float gv = __shfl(pv, srcg, 64);
        float ov = __shfl(pv, srco, 64);
        float cn = cst[nt][r] * fv + pv * gv;    // pv == i on lanes n<4
        float hn = ov * fast_tanh(cn);
        cst[nt][r] = cn;
        // pack 4 adjacent h-cols with seq t+1 into two 8B stores from n==0
        float h1 = __shfl(hn, qb | 1, 64);
        float h2 = __shfl(hn, qb | 2, 64);
        float h3 = __shfl(hn, qb | 3, 64);
        if (n == 0) {
          int m = mbase + quad * 4 + r;
          int c0 = cg * 32 + wave * 8 + nt * 4;
          u32 seq = (u32)(t + 1);
          u64 lo = (u64)pack_hs(hn, seq) | ((u64)pack_hs(h1, seq) << 32);
          u64 hi = (u64)pack_hs(h2, seq) | ((u64)pack_hs(h3, seq) << 32);
          u64* hp = (u64*)(slot_wr + (size_t)m * HID + c0);
          st_agent(hp + 0, lo);
          st_agent(hp + 1, hi);
          if (t == T_STEPS - 1) {
            float4 o4 = {hn, h1, h2, h3};
            *(float4*)(out + (size_t)m * HID + c0) = o4;
          }
        }
      }
    }
    // no end-of-step barrier: next step's poll provides all ordering
  }

  // ---- final fc: out2[b][o] = hT @ Wfc^T + bfc (blocks 0..7, 16 cols each) ----
  if (bid < 8) {
    // h_T = h_1024 lives in slot 0 with seq == T_STEPS. Poll this thread's
    // 1/256 share (128 u64) until all seqs valid; then plain reads are stable.
    {
      const u64* ps = (const u64*)hw + (size_t)tid * 128;
      bool done = false;
      while (true) {
        if (!done) {
          bool v = true;
          for (int j = 0; j < 128; ++j) {
            u64 e = ld_agent(ps + j);
            v &= (((e >> 16) & 0xffffu) == (u32)T_STEPS);
          }
          if (v) done = true;
        }
        if (__all(done)) break;
        __builtin_amdgcn_s_sleep(1);
      }
    }
    __syncthreads();
    float* out2 = out + BATCH * HID;
    int col = bid * 16 + n;
    float bcv = bfc[col];
#pragma unroll
    for (int mt = 0; mt < 2; ++mt) {
      int mb = wave * 32 + mt * 16;
      f32x4 a4 = {bcv, bcv, bcv, bcv};
      const u64* ar = (const u64*)hw + (size_t)(mb + n) * (HID / 2) + quad * 4;
      const float* br = Wfc + col * HID + quad * 8;
#pragma unroll
      for (int k = 0; k < 16; ++k) {
        const u64* p = ar + k * 16;
        bf16x8 A = seq8(ld_agent(p), ld_agent(p + 1), ld_agent(p + 2), ld_agent(p + 3));
        bf16x8 B = cvt8(br + k * 32);
        a4 = mfma_bf16(A, B, a4);
      }
#pragma unroll
      for (int r = 0; r < 4; ++r) {
        out2[(mb + quad * 4 + r) * 128 + col] = a4[r];
      }
    }
  }
}

extern "C" void kernel_launch(void* const* d_in, const int* in_sizes, int n_in,
                              void* d_out, int out_size, void* d_ws, size_t ws_size,
                              hipStream_t stream) {
  (void)in_sizes; (void)n_in; (void)out_size; (void)ws_size;
  const float* x   = (const float*)d_in[0];
  const float* Wx  = (const float*)d_in[2];
  const float* bx  = (const float*)d_in[3];
  const float* Wh  = (const float*)d_in[4];
  const float* bh  = (const float*)d_in[5];
  const float* Wfc = (const float*)d_in[8];
  const float* bfc = (const float*)d_in[9];
  float* out = (float*)d_out;
  u32* hw = (u32*)d_ws;

  // zero ring: (seq 0 | h 0) == valid h_0 state for the t=0 poll. Re-poisoned
  // before every launch by the harness-visible memset below.
  hipMemsetAsync(d_ws, 0, (size_t)2 * BATCH * HID * sizeof(u32), stream);
  lstm_persist<<<dim3(NB), dim3(256), 0, stream>>>(x, Wx, bx, Wh, bh, Wfc, bfc,
                                                   out, hw);
}